// Round 9
// baseline (21.628 us; speedup 1.0000x reference)
//
#include <hip/hip_runtime.h>
#include <math.h>

#define NN 1024
#define DE 64
#define DCAT 22
#define GC 2
#define NTC 512
#define NWAVE (NTC/64)   // 8
#define NBLK (NN/GC)     // 512

// Full-wave (64-lane) sum via DPP; result valid in lane 63. Pure VALU.
__device__ __forceinline__ float wave_sum(float v) {
    int t;
    t = __builtin_amdgcn_update_dpp(0, __float_as_int(v), 0x111, 0xf, 0xf, true); v += __int_as_float(t); // row_shr:1
    t = __builtin_amdgcn_update_dpp(0, __float_as_int(v), 0x112, 0xf, 0xf, true); v += __int_as_float(t); // row_shr:2
    t = __builtin_amdgcn_update_dpp(0, __float_as_int(v), 0x114, 0xf, 0xf, true); v += __int_as_float(t); // row_shr:4
    t = __builtin_amdgcn_update_dpp(0, __float_as_int(v), 0x118, 0xf, 0xf, true); v += __int_as_float(t); // row_shr:8
    t = __builtin_amdgcn_update_dpp(0, __float_as_int(v), 0x142, 0xf, 0xf, true); v += __int_as_float(t); // row_bcast:15
    t = __builtin_amdgcn_update_dpp(0, __float_as_int(v), 0x143, 0xf, 0xf, true); v += __int_as_float(t); // row_bcast:31
    return v;
}

// Single fused kernel: each block owns GC centres; per-node basis (x, vi, gr, gv)
// lives purely in the registers of the thread that sweeps those nodes in phase 2.
__global__ __launch_bounds__(NTC, 4) void nce_fused(
    const float* __restrict__ nc,
    const float* __restrict__ Wq_i, const float* __restrict__ Wk_i,
    const float* __restrict__ Wv_i, const float* __restrict__ Wq_e,
    const float* __restrict__ Wk_e, const float* __restrict__ Wv_e,
    const float* __restrict__ wg,  const float* __restrict__ bgp,
    float* __restrict__ out)
{
    __shared__ float  s_wqi[96], s_wki[96], s_wvi[96], s_wg[64];
    __shared__ float  s_wqe[384], s_wke[1408], s_wve[1408];
    __shared__ float  s_M[6*DCAT], s_Mi[36], s_u[DCAT];
    __shared__ float  s_q[GC][32];
    __shared__ float2 s_red1[NWAVE], s_red2[NWAVE];
    __shared__ float2 s_acc[NWAVE][DCAT];
    __shared__ float  s_fin[DCAT*GC];

    const int tid  = threadIdx.x, wave = tid >> 6, lane = tid & 63;
    const int c0   = blockIdx.x * GC;
    const int nA   = tid, nB = tid + NTC;

    // ---- issue per-node feature loads early (hide under staging) ----
    float xA[6], xB[6];
    #pragma unroll
    for (int f = 0; f < 6; ++f) { xA[f] = nc[nA*6 + f]; xB[f] = nc[nB*6 + f]; }

    // ---- phase 0: stage weights into LDS ----
    if (tid < 96) { s_wqi[tid] = Wq_i[tid]; s_wki[tid] = Wk_i[tid]; s_wvi[tid] = Wv_i[tid]; }
    else if (tid >= 128 && tid < 192) s_wg[tid-128] = wg[tid-128];
    if (tid < 384) s_wqe[tid] = Wq_e[tid];
    for (int i = tid; i < 1408; i += NTC) { s_wke[i] = Wk_e[i]; s_wve[i] = Wv_e[i]; }
    __syncthreads();

    // ---- phase 1a: weight contractions (redundant per block, tiny) ----
    if (tid < 132) {                       // M[f][k] = (Wq_e Wk_e^T)[f,k] / 8
        const int f = tid % 6, k = tid / 6;
        float a = 0.f;
        #pragma unroll
        for (int d = 0; d < 64; ++d) a += s_wqe[f*64+d]*s_wke[k*64+d];
        s_M[f*DCAT+k] = a * 0.125f;
    } else if (tid < 168) {                // Mi[g][f] = (Wq_i Wk_i^T)[g,f] / 4
        const int t = tid - 132, g = t % 6, f = t / 6;
        float a = 0.f;
        #pragma unroll
        for (int j = 0; j < 16; ++j) a += s_wqi[g*16+j]*s_wki[f*16+j];
        s_Mi[g*6+f] = a * 0.25f;
    } else if (tid < 190) {                // u[k] = Wv_e[k,:]·wg
        const int k = tid - 168;
        float a = 0.f;
        #pragma unroll
        for (int d = 0; d < 64; ++d) a += s_wve[k*64+d]*s_wg[d];
        s_u[k] = a;
    }
    __syncthreads();

    // ---- phase 1b: per-node basis in registers; per-centre queries in LDS ----
    float viA[16], viB[16];
    #pragma unroll
    for (int j = 0; j < 16; ++j) {
        float a = 0.f, b = 0.f;
        #pragma unroll
        for (int f = 0; f < 6; ++f) { a += xA[f]*s_wvi[f*16+j]; b += xB[f]*s_wvi[f*16+j]; }
        viA[j] = a; viB[j] = b;
    }
    float grA = 0.f, grB = 0.f, gvA = 0.f, gvB = 0.f;
    #pragma unroll
    for (int f = 0; f < 6; ++f)  { grA += xA[f]*s_u[f];    grB += xB[f]*s_u[f]; }
    #pragma unroll
    for (int j = 0; j < 16; ++j) { gvA += viA[j]*s_u[6+j]; gvB += viB[j]*s_u[6+j]; }

    if (tid < GC*32) {                     // query vectors for this block's centres
        const int c = tid >> 5, k = tid & 31;
        float xc[6];
        #pragma unroll
        for (int f = 0; f < 6; ++f) xc[f] = nc[(c0+c)*6 + f];
        float a = 0.f;
        if (k < 6) {                       // qi2 (scale folded into Mi)
            #pragma unroll
            for (int g = 0; g < 6; ++g) a += xc[g]*s_Mi[g*6+k];
        } else if (k >= 8 && k < 14) {     // qr (scale folded into M)
            #pragma unroll
            for (int f = 0; f < 6; ++f) a += xc[f]*s_M[f*DCAT + (k-8)];
        } else if (k >= 16) {              // qv2
            #pragma unroll
            for (int f = 0; f < 6; ++f) a += xc[f]*s_M[f*DCAT + 6 + (k-16)];
        }
        s_q[c][k] = a;
    }
    const float bg = *bgp;
    __syncthreads();

    // ---------------- stage 1: a_i = softmax_n(qi2[c]·x[n]) ----------------
    float aiA[GC], aiB[GC];
    #pragma unroll
    for (int c = 0; c < GC; ++c) {
        const float* q = s_q[c];
        float sA = 0.f, sB = 0.f;
        #pragma unroll
        for (int f = 0; f < 6; ++f) { sA += q[f]*xA[f]; sB += q[f]*xB[f]; }
        aiA[c] = __expf(sA); aiB[c] = __expf(sB);
    }
    {
        float r0 = wave_sum(aiA[0]+aiB[0]);
        float r1 = wave_sum(aiA[1]+aiB[1]);
        if (lane == 63) s_red1[wave] = make_float2(r0, r1);
    }
    __syncthreads();
    {
        float2 dd = s_red1[0];
        #pragma unroll
        for (int w2 = 1; w2 < NWAVE; ++w2) { float2 t = s_red1[w2]; dd.x += t.x; dd.y += t.y; }
        float inv0 = 1.f/dd.x, inv1 = 1.f/dd.y;
        aiA[0] *= inv0; aiB[0] *= inv0; aiA[1] *= inv1; aiB[1] *= inv1;
    }

    // --------- stage 2: a_e = softmax_n(qr·x + ai*(qv2·Vi)); gate -> w1,w2 ---------
    float w1A[GC], w2A[GC], w1B[GC], w2B[GC];
    {
        float eA[GC], eB[GC];
        #pragma unroll
        for (int c = 0; c < GC; ++c) {
            const float* q = s_q[c];
            float uA = 0.f, uB = 0.f, vA = 0.f, vB = 0.f;
            #pragma unroll
            for (int f = 0; f < 6; ++f) { uA += q[8+f]*xA[f]; uB += q[8+f]*xB[f]; }
            #pragma unroll
            for (int j = 0; j < 16; ++j) { vA += q[16+j]*viA[j]; vB += q[16+j]*viB[j]; }
            eA[c] = __expf(uA + aiA[c]*vA);
            eB[c] = __expf(uB + aiB[c]*vB);
        }
        float s0 = wave_sum(eA[0]+eB[0]);
        float s1 = wave_sum(eA[1]+eB[1]);
        if (lane == 63) s_red2[wave] = make_float2(s0, s1);
        __syncthreads();
        float2 dd = s_red2[0];
        #pragma unroll
        for (int w2 = 1; w2 < NWAVE; ++w2) { float2 t = s_red2[w2]; dd.x += t.x; dd.y += t.y; }
        float den[GC] = {dd.x, dd.y};
        #pragma unroll
        for (int c = 0; c < GC; ++c) {
            float inv = 1.f/den[c];
            float aeA = eA[c]*inv, aeB = eB[c]*inv;
            float preA = aeA*(grA + aiA[c]*gvA) + bg;
            float preB = aeB*(grB + aiB[c]*gvB) + bg;
            float gA = 1.f/(1.f + __expf(-preA));
            float gB = 1.f/(1.f + __expf(-preB));
            w1A[c] = gA*aeA; w2A[c] = w1A[c]*aiA[c];
            w1B[c] = gB*aeB; w2B[c] = w1B[c]*aiB[c];
        }
    }

    // ------- stage 3: xbar[c] = Σ w1·x, vbar[c] = Σ w2·Vi  (DPP block reduce) -------
    #pragma unroll
    for (int f = 0; f < 6; ++f) {
        float a0 = wave_sum(w1A[0]*xA[f] + w1B[0]*xB[f]);
        float a1 = wave_sum(w1A[1]*xA[f] + w1B[1]*xB[f]);
        if (lane == 63) s_acc[wave][f] = make_float2(a0, a1);
    }
    #pragma unroll
    for (int j = 0; j < 16; ++j) {
        float a0 = wave_sum(w2A[0]*viA[j] + w2B[0]*viB[j]);
        float a1 = wave_sum(w2A[1]*viA[j] + w2B[1]*viB[j]);
        if (lane == 63) s_acc[wave][6+j] = make_float2(a0, a1);
    }
    __syncthreads();
    if (tid < DCAT*GC) {                   // 44 threads: sum wave partials
        const int k = tid >> 1, c = tid & 1;
        float a = 0.f;
        #pragma unroll
        for (int w2 = 0; w2 < NWAVE; ++w2)
            a += ((const float*)&s_acc[w2][k])[c];
        s_fin[k*GC + c] = a;
    }
    __syncthreads();

    // ---------------- epilogue: out[c,:] = Wv_e^T [xbar; vbar] ----------------
    if (tid < GC*DE) {
        const int c = tid >> 6, d = tid & 63;
        float o = 0.f;
        #pragma unroll
        for (int k = 0; k < DCAT; ++k) o += s_fin[k*GC + c]*s_wve[k*64 + d];
        out[(c0 + c)*DE + d] = o;
    }
}

extern "C" void kernel_launch(void* const* d_in, const int* in_sizes, int n_in,
                              void* d_out, int out_size, void* d_ws, size_t ws_size,
                              hipStream_t stream)
{
    const float* nc   = (const float*)d_in[0];
    const float* Wq_i = (const float*)d_in[1];
    const float* Wk_i = (const float*)d_in[2];
    const float* Wv_i = (const float*)d_in[3];
    const float* Wq_e = (const float*)d_in[4];
    const float* Wk_e = (const float*)d_in[5];
    const float* Wv_e = (const float*)d_in[6];
    const float* wg   = (const float*)d_in[7];
    const float* bg   = (const float*)d_in[8];
    float* out = (float*)d_out;

    nce_fused<<<NBLK, NTC, 0, stream>>>(nc, Wq_i, Wk_i, Wv_i, Wq_e, Wk_e, Wv_e,
                                        wg, bg, out);
}

// Round 10
// 19.845 us; speedup vs baseline: 1.0899x; 1.0899x over previous
//
#include <hip/hip_runtime.h>
#include <math.h>

#define NN 1024
#define DE 64
#define DCAT 22
#define GC 2
#define NTC 512
#define NWAVE (NTC/64)   // 8
#define NBLK (NN/GC)     // 512

// ws float offsets
#define OFF_M   0                      // [6][22]  M = Wq_e·Wk_e^T / 8
#define OFF_MI  132                    // [6][6]   Mi = Wq_i·Wk_i^T / 4
#define OFF_U   168                    // [22]     u = Wv_e·wg
#define OFF_XT  192                    // [6][NN]  node features transposed
#define OFF_VIT (OFF_XT + 6*NN)        // [16][NN] Vi transposed

// 64-lane sum via DPP (result in lane 63)
__device__ __forceinline__ float wave_sum(float v) {
    int t;
    t = __builtin_amdgcn_update_dpp(0, __float_as_int(v), 0x111, 0xf, 0xf, true); v += __int_as_float(t);
    t = __builtin_amdgcn_update_dpp(0, __float_as_int(v), 0x112, 0xf, 0xf, true); v += __int_as_float(t);
    t = __builtin_amdgcn_update_dpp(0, __float_as_int(v), 0x114, 0xf, 0xf, true); v += __int_as_float(t);
    t = __builtin_amdgcn_update_dpp(0, __float_as_int(v), 0x118, 0xf, 0xf, true); v += __int_as_float(t);
    t = __builtin_amdgcn_update_dpp(0, __float_as_int(v), 0x142, 0xf, 0xf, true); v += __int_as_float(t);
    t = __builtin_amdgcn_update_dpp(0, __float_as_int(v), 0x143, 0xf, 0xf, true); v += __int_as_float(t);
    return v;
}
// 16-lane-row sum (result in lanes 15/31/47/63)
__device__ __forceinline__ float wave_sum16(float v) {
    int t;
    t = __builtin_amdgcn_update_dpp(0, __float_as_int(v), 0x111, 0xf, 0xf, true); v += __int_as_float(t);
    t = __builtin_amdgcn_update_dpp(0, __float_as_int(v), 0x112, 0xf, 0xf, true); v += __int_as_float(t);
    t = __builtin_amdgcn_update_dpp(0, __float_as_int(v), 0x114, 0xf, 0xf, true); v += __int_as_float(t);
    t = __builtin_amdgcn_update_dpp(0, __float_as_int(v), 0x118, 0xf, 0xf, true); v += __int_as_float(t);
    return v;
}

// k1: weight contractions (conflict-free, DPP) + per-node basis, 4 blocks x 256.
__global__ __launch_bounds__(256) void nce_pre(
    const float* __restrict__ nc,
    const float* __restrict__ Wq_i, const float* __restrict__ Wk_i,
    const float* __restrict__ Wv_i, const float* __restrict__ Wq_e,
    const float* __restrict__ Wk_e, const float* __restrict__ Wv_e,
    const float* __restrict__ wg, float* __restrict__ ws)
{
    __shared__ float s_wqi[96], s_wki[96], s_wvi[96], s_wg[64];
    __shared__ float s_wqe[384], s_wke[1408], s_wve[1408];
    const int tid = threadIdx.x, bid = blockIdx.x;
    const int wv = tid >> 6, lane = tid & 63;

    if (tid < 96) { s_wqi[tid] = Wq_i[tid]; s_wki[tid] = Wk_i[tid]; s_wvi[tid] = Wv_i[tid]; }
    if (tid >= 96 && tid < 160) s_wg[tid-96] = wg[tid-96];
    for (int i = tid; i < 384; i += 256) s_wqe[i] = Wq_e[i];
    for (int i = tid; i < 1408; i += 256) { s_wke[i] = Wk_e[i]; s_wve[i] = Wv_e[i]; }
    __syncthreads();

    // contractions: entry list 0..131 = M, 132..167 = Mi, 168..189 = u
    for (int e = bid*4 + wv; e < 190; e += 16) {
        float p; int dst; float scale;
        if (e < 132) {
            const int f = e % 6, k = e / 6;
            p = s_wqe[f*64 + lane] * s_wke[k*64 + lane];   // lane=d: coalesced banks
            dst = OFF_M + f*22 + k; scale = 0.125f;
        } else if (e < 168) {
            const int t = e - 132, g = t % 6, f = t / 6;
            p = (lane < 16) ? s_wqi[g*16 + lane] * s_wki[f*16 + lane] : 0.f;
            dst = OFF_MI + g*6 + f; scale = 0.25f;
        } else {
            const int k = e - 168;
            p = s_wve[k*64 + lane] * s_wg[lane];
            dst = OFF_U + k; scale = 1.f;
        }
        float ssum = wave_sum(p);
        if (lane == 63) ws[dst] = ssum * scale;
    }

    // per-node basis: x (copied transposed) and vi = x·Wv_i (transposed)
    const int n = bid*256 + tid;
    float x[6];
    #pragma unroll
    for (int f = 0; f < 6; ++f) { x[f] = nc[n*6 + f]; ws[OFF_XT + f*NN + n] = x[f]; }
    #pragma unroll
    for (int j = 0; j < 16; ++j) {
        float a = 0.f;
        #pragma unroll
        for (int f = 0; f < 6; ++f) a += x[f]*s_wvi[f*16 + j];
        ws[OFF_VIT + j*NN + n] = a;
    }
}

// k2: per-centre attention in the 22-d basis.
__global__ __launch_bounds__(NTC, 4) void nce_centre(
    const float* __restrict__ ws, const float* __restrict__ nc,
    const float* __restrict__ Wv_e, const float* __restrict__ bgp,
    float* __restrict__ out)
{
    __shared__ float  s_c[192];                 // M(132) Mi(36) u(22)
    __shared__ float  s_wve[DCAT*DE];
    __shared__ __align__(16) float s_q[GC][32]; // 0-5 qi2 | 8-13 qr | 16-31 qv2 (6,7,14,15 = 0)
    __shared__ float2 s_red1[NWAVE], s_red2[NWAVE];
    __shared__ float2 s_acc[32][DCAT];
    __shared__ float  s_fin[DCAT*GC];

    const int tid = threadIdx.x, wave = tid >> 6, lane = tid & 63;
    const int c0 = blockIdx.x * GC;
    const int nA = tid, nB = tid + NTC;

    // issue per-node basis loads early (coalesced row reads from ws)
    float xA[6], xB[6], viA[16], viB[16];
    #pragma unroll
    for (int f = 0; f < 6; ++f) { xA[f] = ws[OFF_XT + f*NN + nA]; xB[f] = ws[OFF_XT + f*NN + nB]; }
    #pragma unroll
    for (int j = 0; j < 16; ++j) { viA[j] = ws[OFF_VIT + j*NN + nA]; viB[j] = ws[OFF_VIT + j*NN + nB]; }

    if (tid < 192) s_c[tid] = (tid < 190) ? ws[tid] : 0.f;
    if (tid < 352) ((float4*)s_wve)[tid] = ((const float4*)Wv_e)[tid];
    if (tid >= 448) ((float*)s_q)[tid-448] = 0.f;   // zero the 64 q slots (incl. pads)
    const float bg = *bgp;
    __syncthreads();

    // queries for this block's 2 centres (64 threads)
    if (tid < GC*32) {
        const int c = tid >> 5, k = tid & 31;
        float xc[6];
        #pragma unroll
        for (int f = 0; f < 6; ++f) xc[f] = nc[(c0+c)*6 + f];
        float a = 0.f; bool live = true;
        if (k < 6) {
            #pragma unroll
            for (int g = 0; g < 6; ++g) a += xc[g]*s_c[OFF_MI + g*6 + k];
        } else if (k >= 8 && k < 14) {
            #pragma unroll
            for (int f = 0; f < 6; ++f) a += xc[f]*s_c[OFF_M + f*22 + (k-8)];
        } else if (k >= 16) {
            #pragma unroll
            for (int f = 0; f < 6; ++f) a += xc[f]*s_c[OFF_M + f*22 + 6 + (k-16)];
        } else live = false;
        if (live) s_q[c][k] = a;
    }
    // gr/gv from u (broadcast LDS reads)
    float grA = 0.f, grB = 0.f, gvA = 0.f, gvB = 0.f;
    #pragma unroll
    for (int f = 0; f < 6; ++f)  { grA += xA[f]*s_c[OFF_U + f];    grB += xB[f]*s_c[OFF_U + f]; }
    #pragma unroll
    for (int j = 0; j < 16; ++j) { gvA += viA[j]*s_c[OFF_U + 6+j]; gvB += viB[j]*s_c[OFF_U + 6+j]; }
    __syncthreads();

    // ---------------- stage 1: a_i softmax ----------------
    float aiA[GC], aiB[GC];
    #pragma unroll
    for (int c = 0; c < GC; ++c) {
        const float4* q4 = (const float4*)s_q[c];
        float4 q0 = q4[0], q1 = q4[1];
        float sA = q0.x*xA[0] + q0.y*xA[1] + q0.z*xA[2] + q0.w*xA[3] + q1.x*xA[4] + q1.y*xA[5];
        float sB = q0.x*xB[0] + q0.y*xB[1] + q0.z*xB[2] + q0.w*xB[3] + q1.x*xB[4] + q1.y*xB[5];
        aiA[c] = __expf(sA); aiB[c] = __expf(sB);
    }
    {
        float r0 = wave_sum(aiA[0]+aiB[0]);
        float r1 = wave_sum(aiA[1]+aiB[1]);
        if (lane == 63) s_red1[wave] = make_float2(r0, r1);
    }
    __syncthreads();
    {
        float2 dd = s_red1[0];
        #pragma unroll
        for (int w2 = 1; w2 < NWAVE; ++w2) { float2 t = s_red1[w2]; dd.x += t.x; dd.y += t.y; }
        float inv0 = 1.f/dd.x, inv1 = 1.f/dd.y;
        aiA[0] *= inv0; aiB[0] *= inv0; aiA[1] *= inv1; aiB[1] *= inv1;
    }

    // ------- stage 2: a_e softmax + gate -> w1,w2 -------
    float w1A[GC], w2A[GC], w1B[GC], w2B[GC];
    {
        float eA[GC], eB[GC];
        #pragma unroll
        for (int c = 0; c < GC; ++c) {
            const float4* q4 = (const float4*)s_q[c];
            float4 q2 = q4[2], q3 = q4[3];
            float uA = q2.x*xA[0] + q2.y*xA[1] + q2.z*xA[2] + q2.w*xA[3] + q3.x*xA[4] + q3.y*xA[5];
            float uB = q2.x*xB[0] + q2.y*xB[1] + q2.z*xB[2] + q2.w*xB[3] + q3.x*xB[4] + q3.y*xB[5];
            float vA = 0.f, vB = 0.f;
            #pragma unroll
            for (int h = 0; h < 4; ++h) {
                float4 qq = q4[4+h];
                vA += qq.x*viA[h*4+0] + qq.y*viA[h*4+1] + qq.z*viA[h*4+2] + qq.w*viA[h*4+3];
                vB += qq.x*viB[h*4+0] + qq.y*viB[h*4+1] + qq.z*viB[h*4+2] + qq.w*viB[h*4+3];
            }
            eA[c] = __expf(uA + aiA[c]*vA);
            eB[c] = __expf(uB + aiB[c]*vB);
        }
        float s0 = wave_sum(eA[0]+eB[0]);
        float s1 = wave_sum(eA[1]+eB[1]);
        if (lane == 63) s_red2[wave] = make_float2(s0, s1);
        __syncthreads();
        float2 dd = s_red2[0];
        #pragma unroll
        for (int w2 = 1; w2 < NWAVE; ++w2) { float2 t = s_red2[w2]; dd.x += t.x; dd.y += t.y; }
        float den[GC] = {dd.x, dd.y};
        #pragma unroll
        for (int c = 0; c < GC; ++c) {
            float inv = 1.f/den[c];
            float aeA = eA[c]*inv, aeB = eB[c]*inv;
            float preA = aeA*(grA + aiA[c]*gvA) + bg;
            float preB = aeB*(grB + aiB[c]*gvB) + bg;
            float gA = 1.f/(1.f + __expf(-preA));
            float gB = 1.f/(1.f + __expf(-preB));
            w1A[c] = gA*aeA; w2A[c] = w1A[c]*aiA[c];
            w1B[c] = gB*aeB; w2B[c] = w1B[c]*aiB[c];
        }
    }

    // ------- stage 3: 4-step DPP to 16-lane partials, then 32-row combine -------
    const int row = (wave << 2) + (lane >> 4);
    #pragma unroll
    for (int f = 0; f < 6; ++f) {
        float a0 = wave_sum16(w1A[0]*xA[f] + w1B[0]*xB[f]);
        float a1 = wave_sum16(w1A[1]*xA[f] + w1B[1]*xB[f]);
        if ((lane & 15) == 15) s_acc[row][f] = make_float2(a0, a1);
    }
    #pragma unroll
    for (int j = 0; j < 16; ++j) {
        float a0 = wave_sum16(w2A[0]*viA[j] + w2B[0]*viB[j]);
        float a1 = wave_sum16(w2A[1]*viA[j] + w2B[1]*viB[j]);
        if ((lane & 15) == 15) s_acc[row][6+j] = make_float2(a0, a1);
    }
    __syncthreads();
    if (tid < DCAT*GC) {
        const int k = tid >> 1, c = tid & 1;
        float a = 0.f;
        #pragma unroll
        for (int r = 0; r < 32; ++r) a += ((const float*)&s_acc[r][k])[c];
        s_fin[k*GC + c] = a;
    }
    __syncthreads();

    // ---------------- epilogue: out[c,:] = Wv_e^T [xbar; vbar] ----------------
    if (tid < GC*DE) {
        const int c = tid >> 6, d = tid & 63;
        float o = 0.f;
        #pragma unroll
        for (int k = 0; k < DCAT; ++k) o += s_fin[k*GC + c]*s_wve[k*64 + d];
        out[(c0 + c)*DE + d] = o;
    }
}

extern "C" void kernel_launch(void* const* d_in, const int* in_sizes, int n_in,
                              void* d_out, int out_size, void* d_ws, size_t ws_size,
                              hipStream_t stream)
{
    const float* nc   = (const float*)d_in[0];
    const float* Wq_i = (const float*)d_in[1];
    const float* Wk_i = (const float*)d_in[2];
    const float* Wv_i = (const float*)d_in[3];
    const float* Wq_e = (const float*)d_in[4];
    const float* Wk_e = (const float*)d_in[5];
    const float* Wv_e = (const float*)d_in[6];
    const float* wg   = (const float*)d_in[7];
    const float* bg   = (const float*)d_in[8];
    float* out = (float*)d_out;
    float* ws  = (float*)d_ws;

    nce_pre<<<4, 256, 0, stream>>>(nc, Wq_i, Wk_i, Wv_i, Wq_e, Wk_e, Wv_e, wg, ws);
    nce_centre<<<NBLK, NTC, 0, stream>>>(ws, nc, Wv_e, bg, out);
}

// Round 11
// 19.283 us; speedup vs baseline: 1.1216x; 1.0291x over previous
//
#include <hip/hip_runtime.h>
#include <math.h>

#define NN 1024
#define DE 64
#define DCAT 22
#define GC 2
#define NTC 512
#define NWAVE (NTC/64)   // 8
#define NBLK (NN/GC)     // 512

// ws float offsets
#define OFF_M   0                      // [6][22]  M = Wq_e·Wk_e^T / 8
#define OFF_MI  132                    // [6][6]   Mi = Wq_i·Wk_i^T / 4
#define OFF_U   168                    // [22]     u = Wv_e·wg
#define OFF_XT  192                    // [6][NN]  node features transposed
#define OFF_VIT (OFF_XT + 6*NN)        // [16][NN] Vi transposed

// 64-lane sum via DPP (result in lane 63)
__device__ __forceinline__ float wave_sum(float v) {
    int t;
    t = __builtin_amdgcn_update_dpp(0, __float_as_int(v), 0x111, 0xf, 0xf, true); v += __int_as_float(t);
    t = __builtin_amdgcn_update_dpp(0, __float_as_int(v), 0x112, 0xf, 0xf, true); v += __int_as_float(t);
    t = __builtin_amdgcn_update_dpp(0, __float_as_int(v), 0x114, 0xf, 0xf, true); v += __int_as_float(t);
    t = __builtin_amdgcn_update_dpp(0, __float_as_int(v), 0x118, 0xf, 0xf, true); v += __int_as_float(t);
    t = __builtin_amdgcn_update_dpp(0, __float_as_int(v), 0x142, 0xf, 0xf, true); v += __int_as_float(t);
    t = __builtin_amdgcn_update_dpp(0, __float_as_int(v), 0x143, 0xf, 0xf, true); v += __int_as_float(t);
    return v;
}
// 16-lane-row sum (result in lanes 15/31/47/63)
__device__ __forceinline__ float wave_sum16(float v) {
    int t;
    t = __builtin_amdgcn_update_dpp(0, __float_as_int(v), 0x111, 0xf, 0xf, true); v += __int_as_float(t);
    t = __builtin_amdgcn_update_dpp(0, __float_as_int(v), 0x112, 0xf, 0xf, true); v += __int_as_float(t);
    t = __builtin_amdgcn_update_dpp(0, __float_as_int(v), 0x114, 0xf, 0xf, true); v += __int_as_float(t);
    t = __builtin_amdgcn_update_dpp(0, __float_as_int(v), 0x118, 0xf, 0xf, true); v += __int_as_float(t);
    return v;
}

// k1: weight contractions (conflict-free, DPP) + per-node basis, 4 blocks x 256.
__global__ __launch_bounds__(256) void nce_pre(
    const float* __restrict__ nc,
    const float* __restrict__ Wq_i, const float* __restrict__ Wk_i,
    const float* __restrict__ Wv_i, const float* __restrict__ Wq_e,
    const float* __restrict__ Wk_e, const float* __restrict__ Wv_e,
    const float* __restrict__ wg, float* __restrict__ ws)
{
    __shared__ float s_wqi[96], s_wki[96], s_wvi[96], s_wg[64];
    __shared__ float s_wqe[384], s_wke[1408], s_wve[1408];
    const int tid = threadIdx.x, bid = blockIdx.x;
    const int wv = tid >> 6, lane = tid & 63;

    if (tid < 96) { s_wqi[tid] = Wq_i[tid]; s_wki[tid] = Wk_i[tid]; s_wvi[tid] = Wv_i[tid]; }
    if (tid >= 96 && tid < 160) s_wg[tid-96] = wg[tid-96];
    for (int i = tid; i < 384; i += 256) s_wqe[i] = Wq_e[i];
    for (int i = tid; i < 1408; i += 256) { s_wke[i] = Wk_e[i]; s_wve[i] = Wv_e[i]; }
    __syncthreads();

    // contractions: entry list 0..131 = M, 132..167 = Mi, 168..189 = u
    for (int e = bid*4 + wv; e < 190; e += 16) {
        float p; int dst; float scale;
        if (e < 132) {
            const int f = e % 6, k = e / 6;
            p = s_wqe[f*64 + lane] * s_wke[k*64 + lane];   // lane=d: bank-spread
            dst = OFF_M + f*22 + k; scale = 0.125f;
        } else if (e < 168) {
            const int t = e - 132, g = t % 6, f = t / 6;
            p = (lane < 16) ? s_wqi[g*16 + lane] * s_wki[f*16 + lane] : 0.f;
            dst = OFF_MI + g*6 + f; scale = 0.25f;
        } else {
            const int k = e - 168;
            p = s_wve[k*64 + lane] * s_wg[lane];
            dst = OFF_U + k; scale = 1.f;
        }
        float ssum = wave_sum(p);
        if (lane == 63) ws[dst] = ssum * scale;
    }

    // per-node basis: x (transposed copy) and vi = x·Wv_i (transposed)
    const int n = bid*256 + tid;
    float x[6];
    #pragma unroll
    for (int f = 0; f < 6; ++f) { x[f] = nc[n*6 + f]; ws[OFF_XT + f*NN + n] = x[f]; }
    #pragma unroll
    for (int j = 0; j < 16; ++j) {
        float a = 0.f;
        #pragma unroll
        for (int f = 0; f < 6; ++f) a += x[f]*s_wvi[f*16 + j];
        ws[OFF_VIT + j*NN + n] = a;
    }
}

// k2: per-centre attention in the 22-d basis, minimal phase structure.
__global__ __launch_bounds__(NTC, 4) void nce_centre(
    const float* __restrict__ ws, const float* __restrict__ nc,
    const float* __restrict__ Wv_e, const float* __restrict__ bgp,
    float* __restrict__ out)
{
    __shared__ __align__(16) float s_q[GC][32]; // 0-5 qi2 | 8-13 qr | 16-31 qv2
    __shared__ float2 s_red1[NWAVE], s_red2[NWAVE];
    __shared__ float2 s_acc[32][DCAT];
    __shared__ float  s_fin[DCAT][GC][2];

    const int tid = threadIdx.x, wave = tid >> 6, lane = tid & 63;
    const int c0 = blockIdx.x * GC;
    const int nA = tid, nB = tid + NTC;

    // ---- phase 0: all loads, no LDS staging of constants ----
    float xA[6], xB[6], viA[16], viB[16];
    #pragma unroll
    for (int f = 0; f < 6; ++f) { xA[f] = ws[OFF_XT + f*NN + nA]; xB[f] = ws[OFF_XT + f*NN + nB]; }
    #pragma unroll
    for (int j = 0; j < 16; ++j) { viA[j] = ws[OFF_VIT + j*NN + nA]; viB[j] = ws[OFF_VIT + j*NN + nB]; }

    // gr/gv from u: wave-uniform addresses -> scalar loads
    float grA = 0.f, grB = 0.f, gvA = 0.f, gvB = 0.f;
    #pragma unroll
    for (int f = 0; f < 6; ++f)  { float u = ws[OFF_U + f];    grA += xA[f]*u;  grB += xB[f]*u; }
    #pragma unroll
    for (int j = 0; j < 16; ++j) { float u = ws[OFF_U + 6+j];  gvA += viA[j]*u; gvB += viB[j]*u; }

    // queries for this block's 2 centres, straight from global ws
    if (tid < GC*32) {
        const int c = tid >> 5, k = tid & 31;
        float xc[6];
        #pragma unroll
        for (int f = 0; f < 6; ++f) xc[f] = nc[(c0+c)*6 + f];
        float a = 0.f;
        if (k < 6) {
            #pragma unroll
            for (int g = 0; g < 6; ++g) a += xc[g]*ws[OFF_MI + g*6 + k];
        } else if (k >= 8 && k < 14) {
            #pragma unroll
            for (int f = 0; f < 6; ++f) a += xc[f]*ws[OFF_M + f*22 + (k-8)];
        } else if (k >= 16) {
            #pragma unroll
            for (int f = 0; f < 6; ++f) a += xc[f]*ws[OFF_M + f*22 + 6 + (k-16)];
        }
        s_q[c][k] = a;          // dead slots (6,7,14,15) get 0
    }
    const float bg = *bgp;
    __syncthreads();            // b1

    // ---------------- stage 1: a_i softmax ----------------
    float aiA[GC], aiB[GC];
    #pragma unroll
    for (int c = 0; c < GC; ++c) {
        const float4* q4 = (const float4*)s_q[c];
        float4 q0 = q4[0], q1 = q4[1];
        float sA = q0.x*xA[0] + q0.y*xA[1] + q0.z*xA[2] + q0.w*xA[3] + q1.x*xA[4] + q1.y*xA[5];
        float sB = q0.x*xB[0] + q0.y*xB[1] + q0.z*xB[2] + q0.w*xB[3] + q1.x*xB[4] + q1.y*xB[5];
        aiA[c] = __expf(sA); aiB[c] = __expf(sB);
    }
    {
        float r0 = wave_sum(aiA[0]+aiB[0]);
        float r1 = wave_sum(aiA[1]+aiB[1]);
        if (lane == 63) s_red1[wave] = make_float2(r0, r1);
    }
    __syncthreads();            // b2
    {
        float2 dd = s_red1[0];
        #pragma unroll
        for (int w2 = 1; w2 < NWAVE; ++w2) { float2 t = s_red1[w2]; dd.x += t.x; dd.y += t.y; }
        float inv0 = 1.f/dd.x, inv1 = 1.f/dd.y;
        aiA[0] *= inv0; aiB[0] *= inv0; aiA[1] *= inv1; aiB[1] *= inv1;
    }

    // ------- stage 2: a_e softmax + gate -> w1,w2 -------
    float w1A[GC], w2A[GC], w1B[GC], w2B[GC];
    {
        float eA[GC], eB[GC];
        #pragma unroll
        for (int c = 0; c < GC; ++c) {
            const float4* q4 = (const float4*)s_q[c];
            float4 q2 = q4[2], q3 = q4[3];
            float uA = q2.x*xA[0] + q2.y*xA[1] + q2.z*xA[2] + q2.w*xA[3] + q3.x*xA[4] + q3.y*xA[5];
            float uB = q2.x*xB[0] + q2.y*xB[1] + q2.z*xB[2] + q2.w*xB[3] + q3.x*xB[4] + q3.y*xB[5];
            float vA = 0.f, vB = 0.f;
            #pragma unroll
            for (int h = 0; h < 4; ++h) {
                float4 qq = q4[4+h];
                vA += qq.x*viA[h*4+0] + qq.y*viA[h*4+1] + qq.z*viA[h*4+2] + qq.w*viA[h*4+3];
                vB += qq.x*viB[h*4+0] + qq.y*viB[h*4+1] + qq.z*viB[h*4+2] + qq.w*viB[h*4+3];
            }
            eA[c] = __expf(uA + aiA[c]*vA);
            eB[c] = __expf(uB + aiB[c]*vB);
        }
        float s0 = wave_sum(eA[0]+eB[0]);
        float s1 = wave_sum(eA[1]+eB[1]);
        if (lane == 63) s_red2[wave] = make_float2(s0, s1);
        __syncthreads();        // b3
        float2 dd = s_red2[0];
        #pragma unroll
        for (int w2 = 1; w2 < NWAVE; ++w2) { float2 t = s_red2[w2]; dd.x += t.x; dd.y += t.y; }
        float den[GC] = {dd.x, dd.y};
        #pragma unroll
        for (int c = 0; c < GC; ++c) {
            float inv = 1.f/den[c];
            float aeA = eA[c]*inv, aeB = eB[c]*inv;
            float preA = aeA*(grA + aiA[c]*gvA) + bg;
            float preB = aeB*(grB + aiB[c]*gvB) + bg;
            float gA = 1.f/(1.f + __expf(-preA));
            float gB = 1.f/(1.f + __expf(-preB));
            w1A[c] = gA*aeA; w2A[c] = w1A[c]*aiA[c];
            w1B[c] = gB*aeB; w2B[c] = w1B[c]*aiB[c];
        }
    }

    // ------- stage 3: 16-lane DPP partials -> 32-row combine -------
    const int row = (wave << 2) + (lane >> 4);
    #pragma unroll
    for (int f = 0; f < 6; ++f) {
        float a0 = wave_sum16(w1A[0]*xA[f] + w1B[0]*xB[f]);
        float a1 = wave_sum16(w1A[1]*xA[f] + w1B[1]*xB[f]);
        if ((lane & 15) == 15) s_acc[row][f] = make_float2(a0, a1);
    }
    #pragma unroll
    for (int j = 0; j < 16; ++j) {
        float a0 = wave_sum16(w2A[0]*viA[j] + w2B[0]*viB[j]);
        float a1 = wave_sum16(w2A[1]*viA[j] + w2B[1]*viB[j]);
        if ((lane & 15) == 15) s_acc[row][6+j] = make_float2(a0, a1);
    }
    __syncthreads();            // b4
    if (tid < DCAT*GC*2) {      // 88 threads, 16 rows each
        const int k = tid >> 2, c = (tid >> 1) & 1, h = tid & 1;
        float a = 0.f;
        #pragma unroll
        for (int r = 0; r < 16; ++r)
            a += ((const float*)&s_acc[h*16 + r][k])[c];
        s_fin[k][c][h] = a;
    }
    __syncthreads();            // b5

    // ---- epilogue: out[c,:] = Wv_e^T [xbar; vbar] (Wv_e straight from L1/L2) ----
    if (tid < GC*DE) {
        const int c = tid >> 6, d = tid & 63;
        float o = 0.f;
        #pragma unroll
        for (int k = 0; k < DCAT; ++k)
            o += (s_fin[k][c][0] + s_fin[k][c][1]) * Wv_e[k*64 + d];
        out[(c0 + c)*DE + d] = o;
    }
}

extern "C" void kernel_launch(void* const* d_in, const int* in_sizes, int n_in,
                              void* d_out, int out_size, void* d_ws, size_t ws_size,
                              hipStream_t stream)
{
    const float* nc   = (const float*)d_in[0];
    const float* Wq_i = (const float*)d_in[1];
    const float* Wk_i = (const float*)d_in[2];
    const float* Wv_i = (const float*)d_in[3];
    const float* Wq_e = (const float*)d_in[4];
    const float* Wk_e = (const float*)d_in[5];
    const float* Wv_e = (const float*)d_in[6];
    const float* wg   = (const float*)d_in[7];
    const float* bg   = (const float*)d_in[8];
    float* out = (float*)d_out;
    float* ws  = (float*)d_ws;

    nce_pre<<<4, 256, 0, stream>>>(nc, Wq_i, Wk_i, Wv_i, Wq_e, Wk_e, Wv_e, wg, ws);
    nce_centre<<<NBLK, NTC, 0, stream>>>(ws, nc, Wv_e, bg, out);
}